// Round 1
// baseline (181405.481 us; speedup 1.0000x reference)
//
#include <hip/hip_runtime.h>
#include <stdint.h>

// Problem constants
#define HD       64
#define MM       256
#define BB       1024
#define LL       2048
#define NBLOCK   256
#define SCALE_   0.125f      // 1/sqrt(64)
#define ETHRESH  2.5f

// ---------------- workspace (d_ws) layout, bytes ----------------
#define WS_ESUM   0          // 2048 f32   (zeroed each launch)
#define WS_ECNT   8192       // 2048 u32   (zeroed each launch)
#define WS_WPAIR  16384      // [64][192] float2 (w_ih r-half, w_hh) = 98304B
#define WS_G      114688     // [64][96] u32 packed bf16: embed@Wx^T + b_ih = 24576B
#define WS_HWT    139264     // [64][64] f32 head_w transposed = 16384B
#define WS_W2     155648     // [64][64] f32 wk^T@wq = 16384B
#define WS_D      172032     // [64] f32 bk@wq
#define WS_E      172288     // [64] f32 bq@wk
#define WS_F      172544     // f32 bq.bk
#define WS_TOTAL  172608

// ---------------- main-kernel LDS layout, bytes ----------------
#define LD_WPAIR  0          // 98304
#define LD_G      98304      // 24576
#define LD_HWT    122880     // 16384
#define LD_BHH    139264     // 768
#define LD_HB     140032     // 256
#define LD_RHB    140288     // 4 waves * 64 float2 = 2048
#define LD_HNB    142336     // 4 waves * 64 f32    = 1024
#define LD_W      143360     // 4 waves * 256 f32   = 4096
#define LD_MISC   147456     // s_ent[4], s_cond
#define LDS_BYTES 147712

// phase-0 overlay (same LDS, used before weights are staged)
#define P0_W2     0
#define P0_WVT    16384
#define P0_D      32768
#define P0_E      33024
#define P0_BV     33280
#define P0_F      33536
#define P0_MC     34816      // + wave*16896 : [64][66] f32 memory chunk

__device__ __forceinline__ unsigned bf16r(float x) {
  unsigned u = __float_as_uint(x);
  return (u + 0x7fffu + ((u >> 16) & 1u)) >> 16;
}
__device__ __forceinline__ unsigned pack2(float a, float b) {
  return bf16r(a) | (bf16r(b) << 16);
}
__device__ __forceinline__ float lo16(unsigned u) { return __uint_as_float(u << 16); }
__device__ __forceinline__ float hi16(unsigned u) { return __uint_as_float(u & 0xffff0000u); }

// wave-local LDS visibility: buffers below are per-wave private; wave64 is lockstep,
// so draining lgkm + a compiler memory barrier is sufficient (no s_barrier needed).
#define WAVE_FENCE() asm volatile("s_waitcnt lgkmcnt(0)" ::: "memory")

// =====================================================================
// P1: one-time weight preprocessing into workspace
// =====================================================================
extern "C" __global__ void reactive_pre(
    const float* __restrict__ embed, const float* __restrict__ w_ih,
    const float* __restrict__ w_hh,  const float* __restrict__ b_ih,
    const float* __restrict__ wq,    const float* __restrict__ bq,
    const float* __restrict__ wk,    const float* __restrict__ bk,
    const float* __restrict__ head_w, unsigned char* __restrict__ ws)
{
  const int tid = threadIdx.x;  // 1024 threads, 1 block

  float2* wpair = (float2*)(ws + WS_WPAIR);
  for (int i = tid; i < 64 * 192; i += 1024) {
    int k = i / 192, j = i % 192;
    wpair[i] = make_float2(w_ih[j * 128 + 64 + k], w_hh[j * 64 + k]);
  }
  unsigned* gp = (unsigned*)(ws + WS_G);
  for (int i = tid; i < 64 * 96; i += 1024) {
    int v = i / 96, u = i % 96;
    int j0 = 2 * u, j1 = j0 + 1;
    float g0 = b_ih[j0], g1 = b_ih[j1];
    for (int h = 0; h < 64; ++h) {
      float ev = embed[v * 64 + h];
      g0 = fmaf(ev, w_ih[j0 * 128 + h], g0);
      g1 = fmaf(ev, w_ih[j1 * 128 + h], g1);
    }
    gp[i] = pack2(g0, g1);
  }
  float* hwt = (float*)(ws + WS_HWT);
  for (int i = tid; i < 4096; i += 1024) {
    int h = i >> 6, o = i & 63;
    hwt[i] = head_w[o * 64 + h];
  }
  float* w2 = (float*)(ws + WS_W2);
  for (int i = tid; i < 4096; i += 1024) {
    int h2 = i >> 6, h = i & 63;
    float a = 0.f;
    for (int o = 0; o < 64; ++o) a = fmaf(wk[o * 64 + h2], wq[o * 64 + h], a);
    w2[i] = a;
  }
  if (tid < 64) {
    float a = 0.f, b2 = 0.f;
    for (int o = 0; o < 64; ++o) a  = fmaf(bk[o], wq[o * 64 + tid], a);
    for (int o = 0; o < 64; ++o) b2 = fmaf(bq[o], wk[o * 64 + tid], b2);
    ((float*)(ws + WS_D))[tid] = a;
    ((float*)(ws + WS_E))[tid] = b2;
  }
  if (tid == 0) {
    float a = 0.f;
    for (int o = 0; o < 64; ++o) a = fmaf(bq[o], bk[o], a);
    *(float*)(ws + WS_F) = a;
  }
}

// =====================================================================
// Main persistent kernel: 256 blocks x 256 threads, 1 block/CU,
// one wave per batch element; K'(bf16) + V^T(bf16) resident in VGPRs.
// =====================================================================
extern "C" __global__ void __launch_bounds__(256, 1)
reactive_main(const int* __restrict__ seq, const float* __restrict__ memory,
              const float* __restrict__ wvp, const float* __restrict__ bvp,
              const float* __restrict__ b_hh, const float* __restrict__ head_w,
              const float* __restrict__ head_b, unsigned char* __restrict__ ws,
              float* __restrict__ out)
{
  extern __shared__ __align__(16) unsigned char lds[];
  const int tid  = threadIdx.x;
  const int wave = tid >> 6;
  const int lane = tid & 63;
  const int b    = (int)blockIdx.x * 4 + wave;

  unsigned kp[4][32];   // K'[m][h] bf16 pairs, m = 64*g + lane, pairs over h
  unsigned vt[128];     // V[m][lane] bf16 pairs over m
  float    cm[4];       // c[m] for this lane's 4 m-rows

  // ---------------- phase 0: per-b K', V^T, c into registers ----------------
  {
    float* sW2  = (float*)(lds + P0_W2);
    float* sWVT = (float*)(lds + P0_WVT);
    float* sD   = (float*)(lds + P0_D);
    float* sE   = (float*)(lds + P0_E);
    float* sBV  = (float*)(lds + P0_BV);
    float* sF   = (float*)(lds + P0_F);
    const float* wsW2 = (const float*)(ws + WS_W2);
    for (int i = tid; i < 4096; i += 256) sW2[i] = wsW2[i];
    for (int i = tid; i < 4096; i += 256) {
      int h2 = i >> 6, l = i & 63;
      sWVT[i] = wvp[l * 64 + h2];          // wv transposed
    }
    if (tid < 64) {
      sD[tid] = ((const float*)(ws + WS_D))[tid];
      sE[tid] = ((const float*)(ws + WS_E))[tid];
      sBV[tid] = bvp[tid];
    }
    if (tid == 0) sF[0] = *(const float*)(ws + WS_F);
    __syncthreads();

    float* mc = (float*)(lds + P0_MC + wave * 16896);   // [64][66]
    const float bvl   = sBV[lane];
    const float fscal = sF[0];
    const float* memb = memory + (size_t)b * (MM * HD);

#pragma unroll
    for (int t = 0; t < 4; ++t) {
      __syncthreads();
#pragma unroll 4
      for (int r = 0; r < 64; ++r)
        mc[r * 66 + lane] = memb[(size_t)(t * 64 + r) * 64 + lane];
      __syncthreads();

      // K' row m = 64t + lane : K'[m][h] = mem[m]·W2[:,h] + d[h] ; c = mem[m]·e + f
      float acc[64];
#pragma unroll
      for (int h = 0; h < 64; ++h) acc[h] = sD[h];
      float cacc = fscal;
      for (int h2 = 0; h2 < 64; ++h2) {
        float mv = mc[lane * 66 + h2];
        cacc = fmaf(mv, sE[h2], cacc);
        const float* w2row = sW2 + h2 * 64;
#pragma unroll
        for (int h = 0; h < 64; ++h) acc[h] = fmaf(mv, w2row[h], acc[h]);
      }
      cm[t] = cacc;
#pragma unroll
      for (int u = 0; u < 32; ++u) kp[t][u] = pack2(acc[2 * u], acc[2 * u + 1]);

      // V^T: vt[32t+rp] packs (V[64t+2rp][lane], V[64t+2rp+1][lane])
#pragma unroll
      for (int rp = 0; rp < 32; ++rp) {
        float a0 = bvl, a1 = bvl;
#pragma unroll 4
        for (int h2 = 0; h2 < 64; ++h2) {
          float wvv = sWVT[h2 * 64 + lane];
          a0 = fmaf(mc[(2 * rp) * 66 + h2],     wvv, a0);
          a1 = fmaf(mc[(2 * rp + 1) * 66 + h2], wvv, a1);
        }
        vt[32 * t + rp] = pack2(a0, a1);
      }
    }
    __syncthreads();
  }

  // ---------------- stage recurrence weights into LDS ----------------
  {
    const float4* src = (const float4*)(ws + WS_WPAIR);
    float4* dst = (float4*)(lds + LD_WPAIR);
    for (int i = tid; i < 6144; i += 256) dst[i] = src[i];
    const float4* gsrc = (const float4*)(ws + WS_G);
    float4* gdst = (float4*)(lds + LD_G);
    for (int i = tid; i < 1536; i += 256) gdst[i] = gsrc[i];
    const float4* hsrc = (const float4*)(ws + WS_HWT);
    float4* hdst = (float4*)(lds + LD_HWT);
    for (int i = tid; i < 1024; i += 256) hdst[i] = hsrc[i];
    if (tid < 192) ((float*)(lds + LD_BHH))[tid] = b_hh[tid];
    if (tid < 64)  ((float*)(lds + LD_HB))[tid]  = head_b[tid];
  }
  __syncthreads();

  const float2*   sWP  = (const float2*)(lds + LD_WPAIR);
  const unsigned* sG   = (const unsigned*)(lds + LD_G);
  const float*    sHWT = (const float*)(lds + LD_HWT);
  const float*    sBHH = (const float*)(lds + LD_BHH);
  const float*    sHB  = (const float*)(lds + LD_HB);
  float2* myRHB = (float2*)(lds + LD_RHB) + wave * 64;
  float*  myHNB = (float*)(lds + LD_HNB) + wave * 64;
  float*  myW   = (float*)(lds + LD_W)   + wave * 256;
  float*  sENT  = (float*)(lds + LD_MISC);
  float*  sCOND = (float*)(lds + LD_MISC + 32);
  float*    esum = (float*)(ws + WS_ESUM);
  unsigned* ecnt = (unsigned*)(ws + WS_ECNT);
  const int* seqb = seq + (size_t)b * LL;

  float h_reg = 0.f, r_ret = 0.f;
  int rcount = 0;

  for (int t = 0; t < LL; ++t) {
    int token = seqb[t];
    myRHB[lane] = make_float2(r_ret, h_reg);
    WAVE_FENCE();

    // ---- GRU gates: gi = G[token] + r@Wr^T ; gh = h@Whh^T + b_hh ----
    unsigned gp0 = sG[token * 96 +      (lane >> 1)];
    unsigned gp1 = sG[token * 96 + 32 + (lane >> 1)];
    unsigned gp2 = sG[token * 96 + 64 + (lane >> 1)];
    bool oddl = (lane & 1);
    float gir = oddl ? hi16(gp0) : lo16(gp0);
    float giz = oddl ? hi16(gp1) : lo16(gp1);
    float gin = oddl ? hi16(gp2) : lo16(gp2);
    float ghr = sBHH[lane], ghz = sBHH[lane + 64], ghn = sBHH[lane + 128];
#pragma unroll 8
    for (int k = 0; k < 64; ++k) {
      float2 rh = myRHB[k];
      float2 w0 = sWP[k * 192 + lane];
      float2 w1 = sWP[k * 192 + 64 + lane];
      float2 w2 = sWP[k * 192 + 128 + lane];
      gir = fmaf(rh.x, w0.x, gir);  ghr = fmaf(rh.y, w0.y, ghr);
      giz = fmaf(rh.x, w1.x, giz);  ghz = fmaf(rh.y, w1.y, ghz);
      gin = fmaf(rh.x, w2.x, gin);  ghn = fmaf(rh.y, w2.y, ghn);
    }
    float rg = 1.f / (1.f + __expf(-(gir + ghr)));
    float zg = 1.f / (1.f + __expf(-(giz + ghz)));
    float narg = gin + rg * ghn;
    float eee = __expf(-2.f * narg);
    float ng = (1.f - eee) / (1.f + eee);
    float h_new = (1.f - zg) * ng + zg * h_reg;
    myHNB[lane] = h_new;
    WAVE_FENCE();

    // ---- entropy gate (bf16 head weights; gate is robust) ----
    float lo = sHB[lane];
#pragma unroll 8
    for (int h = 0; h < 64; ++h) lo = fmaf(myHNB[h], sHWT[h * 64 + lane], lo);
    float mx = lo;
#pragma unroll
    for (int off = 32; off; off >>= 1) mx = fmaxf(mx, __shfl_xor(mx, off, 64));
    float pu = __expf(lo - mx);
    float Ss = pu;
#pragma unroll
    for (int off = 32; off; off >>= 1) Ss += __shfl_xor(Ss, off, 64);
    float pr = pu / Ss;
    float ent = pr * __logf(pr + 1e-8f);
#pragma unroll
    for (int off = 32; off; off >>= 1) ent += __shfl_xor(ent, off, 64);
    if (lane == 0) sENT[wave] = -ent;
    __syncthreads();
    if (tid == 0) {  // post partial entropy; overlapped with attention below
      float be = sENT[0] + sENT[1] + sENT[2] + sENT[3];
      __hip_atomic_fetch_add(&esum[t], be, __ATOMIC_RELAXED, __HIP_MEMORY_SCOPE_AGENT);
      __hip_atomic_fetch_add(&ecnt[t], 1u, __ATOMIC_RELEASE, __HIP_MEMORY_SCOPE_AGENT);
    }

    // ---- attention scores: s[m] = (h·K'[m] + c[m]) * SCALE ----
    float s0 = cm[0], s1 = cm[1], s2 = cm[2], s3 = cm[3];
    const float2* hn2 = (const float2*)myHNB;
#pragma unroll
    for (int hp = 0; hp < 32; ++hp) {
      float2 hv = hn2[hp];
      unsigned u0 = kp[0][hp], u1 = kp[1][hp], u2 = kp[2][hp], u3 = kp[3][hp];
      s0 = fmaf(hv.x, lo16(u0), s0); s0 = fmaf(hv.y, hi16(u0), s0);
      s1 = fmaf(hv.x, lo16(u1), s1); s1 = fmaf(hv.y, hi16(u1), s1);
      s2 = fmaf(hv.x, lo16(u2), s2); s2 = fmaf(hv.y, hi16(u2), s2);
      s3 = fmaf(hv.x, lo16(u3), s3); s3 = fmaf(hv.y, hi16(u3), s3);
    }
    s0 *= SCALE_; s1 *= SCALE_; s2 *= SCALE_; s3 *= SCALE_;

    float smax = fmaxf(fmaxf(s0, s1), fmaxf(s2, s3));
#pragma unroll
    for (int off = 32; off; off >>= 1) smax = fmaxf(smax, __shfl_xor(smax, off, 64));
    float e0 = __expf(s0 - smax), e1 = __expf(s1 - smax);
    float e2 = __expf(s2 - smax), e3 = __expf(s3 - smax);
    float Se = e0 + e1 + e2 + e3;
#pragma unroll
    for (int off = 32; off; off >>= 1) Se += __shfl_xor(Se, off, 64);
    myW[lane] = e0; myW[lane + 64] = e1; myW[lane + 128] = e2; myW[lane + 192] = e3;
    WAVE_FENCE();

    // ---- att[lane] = sum_m w[m]*V[m][lane] / Se ----
    float al = 0.f;
    const float4* w4 = (const float4*)myW;
#pragma unroll
    for (int mp = 0; mp < 64; ++mp) {
      float4 wq4 = w4[mp];
      unsigned u0 = vt[2 * mp], u1 = vt[2 * mp + 1];
      al = fmaf(wq4.x, lo16(u0), al);
      al = fmaf(wq4.y, hi16(u0), al);
      al = fmaf(wq4.z, lo16(u1), al);
      al = fmaf(wq4.w, hi16(u1), al);
    }
    al /= Se;

    // ---- global entropy mean -> cond ----
    if (tid == 0) {
      unsigned c;
      do {
        c = __hip_atomic_load(&ecnt[t], __ATOMIC_ACQUIRE, __HIP_MEMORY_SCOPE_AGENT);
        if (c < NBLOCK) __builtin_amdgcn_s_sleep(2);
      } while (c < NBLOCK);
      float es = __hip_atomic_load(&esum[t], __ATOMIC_RELAXED, __HIP_MEMORY_SCOPE_AGENT);
      sCOND[0] = (es * (1.0f / 1024.0f) > ETHRESH) ? 1.f : 0.f;
    }
    __syncthreads();
    bool condv = (sCOND[0] != 0.f);
    r_ret = condv ? al : 0.f;
    h_reg = h_new;
    rcount += condv ? 1 : 0;
  }

  // ---- final logits with f32 head weights ----
  float lof = head_b[lane];
#pragma unroll 8
  for (int h = 0; h < 64; ++h) lof = fmaf(myHNB[h], head_w[lane * 64 + h], lof);
  out[(size_t)b * 64 + lane] = lof;
  if (blockIdx.x == 0 && tid == 0) out[BB * 64] = (float)rcount / (float)LL;
}

// =====================================================================
extern "C" void kernel_launch(void* const* d_in, const int* in_sizes, int n_in,
                              void* d_out, int out_size, void* d_ws, size_t ws_size,
                              hipStream_t stream)
{
  (void)in_sizes; (void)n_in; (void)out_size; (void)ws_size;
  const int*   seq    = (const int*)  d_in[0];
  const float* memory = (const float*)d_in[1];
  const float* embed  = (const float*)d_in[2];
  const float* w_ih   = (const float*)d_in[3];
  const float* w_hh   = (const float*)d_in[4];
  const float* b_ih   = (const float*)d_in[5];
  const float* b_hh   = (const float*)d_in[6];
  const float* wq     = (const float*)d_in[7];
  const float* bq     = (const float*)d_in[8];
  const float* wk     = (const float*)d_in[9];
  const float* bk     = (const float*)d_in[10];
  const float* wv     = (const float*)d_in[11];
  const float* bv     = (const float*)d_in[12];
  const float* head_w = (const float*)d_in[13];
  const float* head_b = (const float*)d_in[14];
  unsigned char* ws   = (unsigned char*)d_ws;
  float* out          = (float*)d_out;

  // zero the per-step barrier slots (esum/ecnt) every call (graph-safe)
  hipMemsetAsync(d_ws, 0, 16384, stream);

  hipLaunchKernelGGL(reactive_pre, dim3(1), dim3(1024), 0, stream,
                     embed, w_ih, w_hh, b_ih, wq, bq, wk, bk, head_w, ws);

  hipFuncSetAttribute((const void*)reactive_main,
                      hipFuncAttributeMaxDynamicSharedMemorySize, LDS_BYTES);
  hipLaunchKernelGGL(reactive_main, dim3(256), dim3(256), LDS_BYTES, stream,
                     seq, memory, wv, bv, b_hh, head_w, head_b, ws, out);
}

// Round 2
// 33844.803 us; speedup vs baseline: 5.3599x; 5.3599x over previous
//
#include <hip/hip_runtime.h>
#include <stdint.h>

// Problem constants
#define HD       64
#define MM       256
#define BB       1024
#define LL       2048
#define NGROUP   16
#define WPG      64          // waves per slot group (1024/16)
#define SCALE_   0.125f      // 1/sqrt(64)

// gate: mean entropy > 2.5  <=>  sum > 2560  <=> fixed(2^20) sum > 2560<<20.
// butterfly over 64 lanes counts each of the 16 groups 4x -> compare 4x.
#define GATE_X4  10737418240ull   // 2560 * 1048576 * 4

// ---------------- workspace (d_ws) layout, bytes ----------------
#define WS_SLOTS  0          // 16 groups * 2048 steps * u64 = 262144 (zeroed each launch)
#define WS_WPAIR  262144     // [64][192] float2 (w_ih r-half, w_hh) = 98304B
#define WS_G      360448     // [64][96] u32 packed bf16: embed@Wx^T + b_ih = 24576B
#define WS_HWT    385024     // [64][64] f32 head_w transposed = 16384B
#define WS_W2     401408     // [64][64] f32 wk^T@wq = 16384B
#define WS_D      417792     // [64] f32 bk@wq
#define WS_E      418048     // [64] f32 bq@wk
#define WS_F      418304     // f32 bq.bk

// ---------------- main-kernel LDS layout, bytes ----------------
#define LD_WPAIR  0          // 98304
#define LD_G      98304      // 24576
#define LD_HWT    122880     // 16384
#define LD_BHH    139264     // 768
#define LD_HB     140032     // 256
#define LD_RHB    140288     // 4 waves * 64 float2 = 2048
#define LD_HNB    142336     // 4 waves * 64 f32    = 1024
#define LD_W      143360     // 4 waves * 256 f32   = 4096
#define LDS_BYTES 147712

// phase-0 overlay (same LDS, used before weights are staged)
#define P0_W2     0
#define P0_WVT    16384
#define P0_D      32768
#define P0_E      33024
#define P0_BV     33280
#define P0_F      33536
#define P0_MC     34816      // + wave*16896 : [64][66] f32 memory chunk

__device__ __forceinline__ unsigned bf16r(float x) {
  unsigned u = __float_as_uint(x);
  return (u + 0x7fffu + ((u >> 16) & 1u)) >> 16;
}
__device__ __forceinline__ unsigned pack2(float a, float b) {
  return bf16r(a) | (bf16r(b) << 16);
}
__device__ __forceinline__ float lo16(unsigned u) { return __uint_as_float(u << 16); }
__device__ __forceinline__ float hi16(unsigned u) { return __uint_as_float(u & 0xffff0000u); }

// wave-local LDS visibility: buffers below are per-wave private; wave64 is lockstep,
// so draining lgkm + a compiler memory barrier is sufficient (no s_barrier needed).
#define WAVE_FENCE() asm volatile("s_waitcnt lgkmcnt(0)" ::: "memory")

// Per-wave resolve of the grid-wide entropy gate for step t.
// Lane l reads slot group (l&15); completion when every group's count==WPG.
// Value+count travel in one u64 -> relaxed atomics suffice (no cache inval).
__device__ __forceinline__ bool poll_cond(const unsigned long long* slots, int t, int lane) {
  const unsigned long long* p = slots + (size_t)(lane & 15) * LL + t;
  unsigned long long v;
  for (;;) {
    v = __hip_atomic_load(p, __ATOMIC_RELAXED, __HIP_MEMORY_SCOPE_AGENT);
    if (__all((int)(v >> 48) == WPG)) break;
    __builtin_amdgcn_s_sleep(1);
  }
  unsigned long long s = v & 0xFFFFFFFFFFFFull;
#pragma unroll
  for (int off = 32; off; off >>= 1) s += __shfl_xor(s, off, 64);
  return s > GATE_X4;
}

// =====================================================================
// P1: one-time weight preprocessing into workspace
// =====================================================================
extern "C" __global__ void reactive_pre(
    const float* __restrict__ embed, const float* __restrict__ w_ih,
    const float* __restrict__ w_hh,  const float* __restrict__ b_ih,
    const float* __restrict__ wq,    const float* __restrict__ bq,
    const float* __restrict__ wk,    const float* __restrict__ bk,
    const float* __restrict__ head_w, unsigned char* __restrict__ ws)
{
  const int tid = threadIdx.x;  // 1024 threads, 1 block

  float2* wpair = (float2*)(ws + WS_WPAIR);
  for (int i = tid; i < 64 * 192; i += 1024) {
    int k = i / 192, j = i % 192;
    wpair[i] = make_float2(w_ih[j * 128 + 64 + k], w_hh[j * 64 + k]);
  }
  unsigned* gp = (unsigned*)(ws + WS_G);
  for (int i = tid; i < 64 * 96; i += 1024) {
    int v = i / 96, u = i % 96;
    int j0 = 2 * u, j1 = j0 + 1;
    float g0 = b_ih[j0], g1 = b_ih[j1];
    for (int h = 0; h < 64; ++h) {
      float ev = embed[v * 64 + h];
      g0 = fmaf(ev, w_ih[j0 * 128 + h], g0);
      g1 = fmaf(ev, w_ih[j1 * 128 + h], g1);
    }
    gp[i] = pack2(g0, g1);
  }
  float* hwt = (float*)(ws + WS_HWT);
  for (int i = tid; i < 4096; i += 1024) {
    int h = i >> 6, o = i & 63;
    hwt[i] = head_w[o * 64 + h];
  }
  float* w2 = (float*)(ws + WS_W2);
  for (int i = tid; i < 4096; i += 1024) {
    int h2 = i >> 6, h = i & 63;
    float a = 0.f;
    for (int o = 0; o < 64; ++o) a = fmaf(wk[o * 64 + h2], wq[o * 64 + h], a);
    w2[i] = a;
  }
  if (tid < 64) {
    float a = 0.f, b2 = 0.f;
    for (int o = 0; o < 64; ++o) a  = fmaf(bk[o], wq[o * 64 + tid], a);
    for (int o = 0; o < 64; ++o) b2 = fmaf(bq[o], wk[o * 64 + tid], b2);
    ((float*)(ws + WS_D))[tid] = a;
    ((float*)(ws + WS_E))[tid] = b2;
  }
  if (tid == 0) {
    float a = 0.f;
    for (int o = 0; o < 64; ++o) a = fmaf(bq[o], bk[o], a);
    *(float*)(ws + WS_F) = a;
  }
}

// =====================================================================
// Main persistent kernel: 256 blocks x 256 threads, 1 block/CU,
// one wave per batch element; K'(bf16) + V^T(bf16) resident in VGPRs.
// Steady loop has NO block barriers: waves sync only via packed u64 slots.
// =====================================================================
extern "C" __global__ void __launch_bounds__(256, 1)
reactive_main(const int* __restrict__ seq, const float* __restrict__ memory,
              const float* __restrict__ wvp, const float* __restrict__ bvp,
              const float* __restrict__ b_hh, const float* __restrict__ head_w,
              const float* __restrict__ head_b, unsigned char* __restrict__ ws,
              float* __restrict__ out)
{
  extern __shared__ __align__(16) unsigned char lds[];
  const int tid  = threadIdx.x;
  const int wave = tid >> 6;
  const int lane = tid & 63;
  const int b    = (int)blockIdx.x * 4 + wave;
  const int grp  = b & (NGROUP - 1);

  unsigned kp[4][32];   // K'[m][h] bf16 pairs, m = 64*g + lane, pairs over h
  unsigned vt[128];     // V[m][lane] bf16 pairs over m
  float    cm[4];       // c[m] for this lane's 4 m-rows

  // ---------------- phase 0: per-b K', V^T, c into registers ----------------
  {
    float* sW2  = (float*)(lds + P0_W2);
    float* sWVT = (float*)(lds + P0_WVT);
    float* sD   = (float*)(lds + P0_D);
    float* sE   = (float*)(lds + P0_E);
    float* sBV  = (float*)(lds + P0_BV);
    float* sF   = (float*)(lds + P0_F);
    const float* wsW2 = (const float*)(ws + WS_W2);
    for (int i = tid; i < 4096; i += 256) sW2[i] = wsW2[i];
    for (int i = tid; i < 4096; i += 256) {
      int h2 = i >> 6, l = i & 63;
      sWVT[i] = wvp[l * 64 + h2];          // wv transposed
    }
    if (tid < 64) {
      sD[tid] = ((const float*)(ws + WS_D))[tid];
      sE[tid] = ((const float*)(ws + WS_E))[tid];
      sBV[tid] = bvp[tid];
    }
    if (tid == 0) sF[0] = *(const float*)(ws + WS_F);
    __syncthreads();

    float* mc = (float*)(lds + P0_MC + wave * 16896);   // [64][66]
    const float bvl   = sBV[lane];
    const float fscal = sF[0];
    const float* memb = memory + (size_t)b * (MM * HD);

#pragma unroll
    for (int t = 0; t < 4; ++t) {
      __syncthreads();
#pragma unroll 4
      for (int r = 0; r < 64; ++r)
        mc[r * 66 + lane] = memb[(size_t)(t * 64 + r) * 64 + lane];
      __syncthreads();

      float acc[64];
#pragma unroll
      for (int h = 0; h < 64; ++h) acc[h] = sD[h];
      float cacc = fscal;
      for (int h2 = 0; h2 < 64; ++h2) {
        float mv = mc[lane * 66 + h2];
        cacc = fmaf(mv, sE[h2], cacc);
        const float* w2row = sW2 + h2 * 64;
#pragma unroll
        for (int h = 0; h < 64; ++h) acc[h] = fmaf(mv, w2row[h], acc[h]);
      }
      cm[t] = cacc;
#pragma unroll
      for (int u = 0; u < 32; ++u) kp[t][u] = pack2(acc[2 * u], acc[2 * u + 1]);

#pragma unroll
      for (int rp = 0; rp < 32; ++rp) {
        float a0 = bvl, a1 = bvl;
#pragma unroll 4
        for (int h2 = 0; h2 < 64; ++h2) {
          float wvv = sWVT[h2 * 64 + lane];
          a0 = fmaf(mc[(2 * rp) * 66 + h2],     wvv, a0);
          a1 = fmaf(mc[(2 * rp + 1) * 66 + h2], wvv, a1);
        }
        vt[32 * t + rp] = pack2(a0, a1);
      }
    }
    __syncthreads();
  }

  // ---------------- stage recurrence weights into LDS ----------------
  {
    const float4* src = (const float4*)(ws + WS_WPAIR);
    float4* dst = (float4*)(lds + LD_WPAIR);
    for (int i = tid; i < 6144; i += 256) dst[i] = src[i];
    const float4* gsrc = (const float4*)(ws + WS_G);
    float4* gdst = (float4*)(lds + LD_G);
    for (int i = tid; i < 1536; i += 256) gdst[i] = gsrc[i];
    const float4* hsrc = (const float4*)(ws + WS_HWT);
    float4* hdst = (float4*)(lds + LD_HWT);
    for (int i = tid; i < 1024; i += 256) hdst[i] = hsrc[i];
    if (tid < 192) ((float*)(lds + LD_BHH))[tid] = b_hh[tid];
    if (tid < 64)  ((float*)(lds + LD_HB))[tid]  = head_b[tid];
  }
  __syncthreads();

  const float2*   sWP  = (const float2*)(lds + LD_WPAIR);
  const unsigned* sG   = (const unsigned*)(lds + LD_G);
  const float*    sHWT = (const float*)(lds + LD_HWT);
  const float*    sBHH = (const float*)(lds + LD_BHH);
  const float*    sHB  = (const float*)(lds + LD_HB);
  float2* myRHB = (float2*)(lds + LD_RHB) + wave * 64;
  float*  myHNB = (float*)(lds + LD_HNB) + wave * 64;
  float*  myW   = (float*)(lds + LD_W)   + wave * 256;
  unsigned long long* slots = (unsigned long long*)(ws + WS_SLOTS);
  const int* seqb = seq + (size_t)b * LL;

  float h_reg = 0.f, al_prev = 0.f;
  int rcount = 0;
  const float ghr_b = sBHH[lane], ghz_b = sBHH[lane + 64], ghn_b = sBHH[lane + 128];

  for (int t = 0; t < LL; ++t) {
    int token = seqb[t];
    myRHB[lane] = make_float2(al_prev, h_reg);
    WAVE_FENCE();

    // ---- GRU partials (speculative: no cond needed) ----
    // gi = G[token] + cond_{t-1} * (al_prev @ Wr^T) ; gh = h @ Whh^T + b_hh
    unsigned gp0 = sG[token * 96 +      (lane >> 1)];
    unsigned gp1 = sG[token * 96 + 32 + (lane >> 1)];
    unsigned gp2 = sG[token * 96 + 64 + (lane >> 1)];
    bool oddl = (lane & 1);
    float g_r = oddl ? hi16(gp0) : lo16(gp0);
    float g_z = oddl ? hi16(gp1) : lo16(gp1);
    float g_n = oddl ? hi16(gp2) : lo16(gp2);
    float girA = 0.f, gizA = 0.f, ginA = 0.f;
    float ghr = ghr_b, ghz = ghz_b, ghn = ghn_b;
#pragma unroll 8
    for (int k = 0; k < 64; ++k) {
      float2 rh = myRHB[k];
      float2 w0 = sWP[k * 192 + lane];
      float2 w1 = sWP[k * 192 + 64 + lane];
      float2 w2 = sWP[k * 192 + 128 + lane];
      girA = fmaf(rh.x, w0.x, girA);  ghr = fmaf(rh.y, w0.y, ghr);
      gizA = fmaf(rh.x, w1.x, gizA);  ghz = fmaf(rh.y, w1.y, ghz);
      ginA = fmaf(rh.x, w2.x, ginA);  ghn = fmaf(rh.y, w2.y, ghn);
    }

    // ---- resolve cond_{t-1} (posted ~3000 cycles ago; usually ready) ----
    bool condp = (t > 0) ? poll_cond(slots, t - 1, lane) : false;
    rcount += condp ? 1 : 0;
    float sel = condp ? 1.f : 0.f;
    float gir = fmaf(sel, girA, g_r);
    float giz = fmaf(sel, gizA, g_z);
    float gin = fmaf(sel, ginA, g_n);

    float rg = 1.f / (1.f + __expf(-(gir + ghr)));
    float zg = 1.f / (1.f + __expf(-(giz + ghz)));
    float narg = gin + rg * ghn;
    float eee = __expf(-2.f * narg);
    float ng = (1.f - eee) / (1.f + eee);
    float h_new = (1.f - zg) * ng + zg * h_reg;
    myHNB[lane] = h_new;
    WAVE_FENCE();

    // ---- entropy gate -> post packed (count|value) with ONE relaxed atomic ----
    float lo = sHB[lane];
#pragma unroll 8
    for (int h = 0; h < 64; ++h) lo = fmaf(myHNB[h], sHWT[h * 64 + lane], lo);
    float mx = lo;
#pragma unroll
    for (int off = 32; off; off >>= 1) mx = fmaxf(mx, __shfl_xor(mx, off, 64));
    float pu = __expf(lo - mx);
    float Ss = pu;
#pragma unroll
    for (int off = 32; off; off >>= 1) Ss += __shfl_xor(Ss, off, 64);
    float pr = pu / Ss;
    float ent = pr * __logf(pr + 1e-8f);
#pragma unroll
    for (int off = 32; off; off >>= 1) ent += __shfl_xor(ent, off, 64);
    if (lane == 0) {
      float be = fmaxf(-ent, 0.f);
      unsigned long long pk = (1ull << 48) | (unsigned long long)(be * 1048576.0f + 0.5f);
      __hip_atomic_fetch_add(&slots[(size_t)grp * LL + t], pk,
                             __ATOMIC_RELAXED, __HIP_MEMORY_SCOPE_AGENT);
    }

    // ---- attention scores: s[m] = (h·K'[m] + c[m]) * SCALE ----
    float s0 = cm[0], s1 = cm[1], s2 = cm[2], s3 = cm[3];
    const float2* hn2 = (const float2*)myHNB;
#pragma unroll
    for (int hp = 0; hp < 32; ++hp) {
      float2 hv = hn2[hp];
      unsigned u0 = kp[0][hp], u1 = kp[1][hp], u2 = kp[2][hp], u3 = kp[3][hp];
      s0 = fmaf(hv.x, lo16(u0), s0); s0 = fmaf(hv.y, hi16(u0), s0);
      s1 = fmaf(hv.x, lo16(u1), s1); s1 = fmaf(hv.y, hi16(u1), s1);
      s2 = fmaf(hv.x, lo16(u2), s2); s2 = fmaf(hv.y, hi16(u2), s2);
      s3 = fmaf(hv.x, lo16(u3), s3); s3 = fmaf(hv.y, hi16(u3), s3);
    }
    s0 *= SCALE_; s1 *= SCALE_; s2 *= SCALE_; s3 *= SCALE_;

    float smax = fmaxf(fmaxf(s0, s1), fmaxf(s2, s3));
#pragma unroll
    for (int off = 32; off; off >>= 1) smax = fmaxf(smax, __shfl_xor(smax, off, 64));
    float e0 = __expf(s0 - smax), e1 = __expf(s1 - smax);
    float e2 = __expf(s2 - smax), e3 = __expf(s3 - smax);
    float Se = e0 + e1 + e2 + e3;
#pragma unroll
    for (int off = 32; off; off >>= 1) Se += __shfl_xor(Se, off, 64);
    myW[lane] = e0; myW[lane + 64] = e1; myW[lane + 128] = e2; myW[lane + 192] = e3;
    WAVE_FENCE();

    // ---- att[lane] = sum_m w[m]*V[m][lane] / Se (unconditional; gated by NEXT step) ----
    float al = 0.f;
    const float4* w4 = (const float4*)myW;
#pragma unroll
    for (int mp = 0; mp < 64; ++mp) {
      float4 wq4 = w4[mp];
      unsigned u0 = vt[2 * mp], u1 = vt[2 * mp + 1];
      al = fmaf(wq4.x, lo16(u0), al);
      al = fmaf(wq4.y, hi16(u0), al);
      al = fmaf(wq4.z, lo16(u1), al);
      al = fmaf(wq4.w, hi16(u1), al);
    }
    al_prev = al / Se;
    h_reg = h_new;
  }

  // resolve the final step's cond (needed only for read_rate)
  rcount += poll_cond(slots, LL - 1, lane) ? 1 : 0;

  // ---- final logits with f32 head weights ----
  float lof = head_b[lane];
#pragma unroll 8
  for (int h = 0; h < 64; ++h) lof = fmaf(myHNB[h], head_w[lane * 64 + h], lof);
  out[(size_t)b * 64 + lane] = lof;
  if (blockIdx.x == 0 && tid == 0) out[BB * 64] = (float)rcount / (float)LL;
}

// =====================================================================
extern "C" void kernel_launch(void* const* d_in, const int* in_sizes, int n_in,
                              void* d_out, int out_size, void* d_ws, size_t ws_size,
                              hipStream_t stream)
{
  (void)in_sizes; (void)n_in; (void)out_size; (void)ws_size;
  const int*   seq    = (const int*)  d_in[0];
  const float* memory = (const float*)d_in[1];
  const float* embed  = (const float*)d_in[2];
  const float* w_ih   = (const float*)d_in[3];
  const float* w_hh   = (const float*)d_in[4];
  const float* b_ih   = (const float*)d_in[5];
  const float* b_hh   = (const float*)d_in[6];
  const float* wq     = (const float*)d_in[7];
  const float* bq     = (const float*)d_in[8];
  const float* wk     = (const float*)d_in[9];
  const float* bk     = (const float*)d_in[10];
  const float* wv     = (const float*)d_in[11];
  const float* bv     = (const float*)d_in[12];
  const float* head_w = (const float*)d_in[13];
  const float* head_b = (const float*)d_in[14];
  unsigned char* ws   = (unsigned char*)d_ws;
  float* out          = (float*)d_out;

  // zero the per-step packed slots every call (graph-safe)
  hipMemsetAsync(d_ws, 0, NGROUP * LL * sizeof(unsigned long long), stream);

  hipLaunchKernelGGL(reactive_pre, dim3(1), dim3(1024), 0, stream,
                     embed, w_ih, w_hh, b_ih, wq, bq, wk, bk, head_w, ws);

  hipFuncSetAttribute((const void*)reactive_main,
                      hipFuncAttributeMaxDynamicSharedMemorySize, LDS_BYTES);
  hipLaunchKernelGGL(reactive_main, dim3(256), dim3(256), LDS_BYTES, stream,
                     seq, memory, wv, bv, b_hh, head_w, head_b, ws, out);
}